// Round 10
// baseline (206.010 us; speedup 1.0000x reference)
//
#include <hip/hip_runtime.h>
#include <stdint.h>

#define BATCH   16
#define PTS     50000
#define PP      2048
#define NPTS    (BATCH*PTS)     // 800000
#define NPAIR   (BATCH*PP)      // 32768
#define NEND    (2*NPAIR)
#define CFEAT   64
#define KIN     128             // folded layer-1 K
#define HID     1024
#define QTS_LOG2 17
#define QTS     (1u<<QTS_LOG2)
#define QTS_MASK (QTS-1)
#define EMPTY_KEY 0xFFFFFFFFFFFFFFFFULL
#define NJB     64
#define RJ      (PP/NJB)        // 32 j's per block, in registers

typedef unsigned long long ull;
typedef __attribute__((ext_vector_type(4))) float f32x4;
typedef __attribute__((ext_vector_type(8))) short bf16x8;

__device__ __forceinline__ ull mix64(ull h) {
  h ^= h >> 33; h *= 0xff51afd7ed558ccdULL;
  h ^= h >> 33; h *= 0xc4ceb9fe1a85ec53ULL;
  h ^= h >> 33; return h;
}

__device__ __forceinline__ unsigned short f2b(float x) {  // fp32->bf16 RNE
  unsigned u = __float_as_uint(x);
  unsigned r = (u + 0x7FFFu + ((u >> 16) & 1u)) >> 16;
  return (unsigned short)r;
}

// ---------------- setup: hash-init + foldW1 + transcvt(W2), one dispatch ---
__global__ __launch_bounds__(256) void setup_kernel(
    ull* __restrict__ qtable, unsigned int* __restrict__ ans,
    const float* __restrict__ W1, unsigned short* __restrict__ Wt1,
    const float* __restrict__ W2, unsigned short* __restrict__ Wt2) {
  __shared__ unsigned short tile[32][33];
  int bid = blockIdx.x;
  int t = threadIdx.x;
  if (bid < 512) {
    int i = bid * 256 + t;                  // QTS = 131072 = 512*256
    qtable[i] = EMPTY_KEY;
    ans[i] = 0xFFFFFFFFu;
  } else if (bid < 1024) {
    int idx = (bid - 512) * 256 + t;        // HID*KIN = 131072
    int n = idx >> 7, k = idx & 127;
    float v;
    if (k < 64)
      v = W1[(size_t)k * HID + n] + W1[(size_t)(128 + k) * HID + n];
    else
      v = W1[(size_t)k * HID + n] - W1[(size_t)(64 + k) * HID + n];
    Wt1[(size_t)n * KIN + k] = f2b(v);
  } else {
    int b = bid - 1024;                     // 1024 blocks: 32x32 tiles of W2
    int nb = (b & 31) * 32, kb = (b >> 5) * 32;
    int tx = t & 31, ty = t >> 5;
#pragma unroll
    for (int r = 0; r < 32; r += 8)
      tile[ty + r][tx] = f2b(W2[(size_t)(kb + ty + r) * HID + nb + tx]);
    __syncthreads();
#pragma unroll
    for (int r = 0; r < 32; r += 8)
      Wt2[(size_t)(nb + ty + r) * HID + kb + tx] = tile[tx][ty + r];
  }
}

// ---------------- insert the 65536 endpoint keys ---------------------------
__global__ void qinsert(const int* __restrict__ pairs, const int* __restrict__ gc,
                        ull* __restrict__ qtable, unsigned int* __restrict__ eslot) {
  int e = blockIdx.x * blockDim.x + threadIdx.x;
  if (e >= NEND) return;
  int j = e >> 1, side = e & 1;
  int seg = j / PP;
  int pi = pairs[2*j + side] + seg * PTS;
  pi = pi < 0 ? 0 : (pi >= NPTS ? NPTS - 1 : pi);
  ull key = ((ull)seg << 30) | ((ull)(gc[3*pi] & 1023) << 20)
          | ((ull)(gc[3*pi+1] & 1023) << 10) | (ull)(gc[3*pi+2] & 1023);
  unsigned int h = (unsigned int)mix64(key) & QTS_MASK;
  for (int p = 0; p < (int)QTS; ++p) {
    ull prev = atomicCAS(&qtable[h], EMPTY_KEY, key);
    if (prev == EMPTY_KEY || prev == key) { eslot[e] = h; return; }
    h = (h + 1) & QTS_MASK;
  }
  eslot[e] = 0;
}

// ---------------- scan all voxels; min row index per queried key -----------
__global__ void vscan(const int* __restrict__ vidx, const ull* __restrict__ qtable,
                      unsigned int* __restrict__ ans) {
  int i = blockIdx.x * blockDim.x + threadIdx.x;
  if (i >= NPTS) return;
  int4 v = *(const int4*)&vidx[4*i];
  ull key = ((ull)(v.x & 31) << 30) | ((ull)(v.y & 1023) << 20)
          | ((ull)(v.z & 1023) << 10) | (ull)(v.w & 1023);
  unsigned int h = (unsigned int)mix64(key) & QTS_MASK;
  for (int p = 0; p < (int)QTS; ++p) {
    ull k = qtable[h];
    if (k == key) { atomicMin(&ans[h], (unsigned int)i); return; }
    if (k == EMPTY_KEY) return;
    h = (h + 1) & QTS_MASK;
  }
}

// ---------------- gemm1 FUSED: gather(A from vf) + 128x128 bf16 MFMA -------
// A-tile k-half kt (64 cols) of row j = f2b(vf[ans[eslot[2j+kt]]][0..63]).
// Reg-staged gather writes the SAME swizzled LDS bytes the verified LDA path
// reads (XOR touches byte-bits 4-6 only -> 8B stores stay aligned).
__global__ __launch_bounds__(256) void gemm1_fused(
    const float* __restrict__ vf, const unsigned int* __restrict__ eslot,
    const unsigned int* __restrict__ ans, const unsigned short* __restrict__ Bt,
    const float* __restrict__ bias, unsigned short* __restrict__ Cb, int M) {
  __shared__ unsigned short As[128 * 64];
  __shared__ unsigned short Bs[128 * 64];
  int t = threadIdx.x;
  int lane = t & 63, w = t >> 6;
  int l15 = lane & 15, lhi = lane >> 4;
  int wm = w >> 1, wn = w & 1;
  int ncol = gridDim.x;
  int stripe, cb;
  if ((gridDim.y & 7) == 0) {
    int h = blockIdx.x + ncol * blockIdx.y;
    stripe = (h & 7) + 8 * (h / (8 * ncol));
    cb = (h >> 3) % ncol;
  } else {
    stripe = blockIdx.y; cb = blockIdx.x;
  }
  int row0 = stripe * 128, col0 = cb * 128;
  const size_t Kb = (size_t)KIN * 2;
  f32x4 acc[4][4] = {};
  const char* Ac = (const char*)As;
  const char* Bc = (const char*)Bs;
  int arow = t >> 1, ahalf = t & 1;
#pragma unroll
  for (int kt = 0; kt < 2; ++kt) {          // k0 = kt*64; side = kt
    // ---- A: gather + f2b + swizzled ds_write (8B stores)
    unsigned int rr = ans[eslot[2 * (row0 + arow) + kt]];
    rr = rr < (unsigned)NPTS ? rr : 0u;     // wrong-value beats mem-fault
    const float* src = vf + (size_t)rr * CFEAT + ahalf * 32;
    char* adst = (char*)As + arow * 128;
    int aswz = (arow & 7) << 4;
#pragma unroll
    for (int i = 0; i < 8; ++i) {
      float4 v = *(const float4*)(src + 4 * i);
      ull o = (ull)f2b(v.x) | ((ull)f2b(v.y) << 16)
            | ((ull)f2b(v.z) << 32) | ((ull)f2b(v.w) << 48);
      *(ull*)(adst + ((ahalf * 64 + 8 * i) ^ aswz)) = o;
    }
    // ---- B: global_load_lds width-16 (source pre-swizzled)
#pragma unroll
    for (int it = 0; it < 4; ++it) {
      int q = (it * 4 + w) * 64 + lane;
      int brow = q >> 3, slot = q & 7;
      int sb = (slot * 16) ^ ((brow & 7) << 4);
      const char* gB = (const char*)Bt + (size_t)(col0 + brow) * Kb
                     + (size_t)kt * 128 + sb;
      char* lB = (char*)Bs + (it * 4 + w) * 1024;
      __builtin_amdgcn_global_load_lds((const __attribute__((address_space(1))) void*)gB,
                                       (__attribute__((address_space(3))) void*)lB, 16, 0, 0);
    }
    __syncthreads();
#pragma unroll
    for (int s = 0; s < 2; ++s) {
      bf16x8 af[4], bfr[4];
#pragma unroll
      for (int mi = 0; mi < 4; ++mi) {
        int row = wm * 64 + mi * 16 + l15;
        int off = row * 128 + ((s * 64 + lhi * 16) ^ ((row & 7) << 4));
        af[mi] = *(const bf16x8*)(Ac + off);
      }
#pragma unroll
      for (int ni = 0; ni < 4; ++ni) {
        int row = wn * 64 + ni * 16 + l15;
        int off = row * 128 + ((s * 64 + lhi * 16) ^ ((row & 7) << 4));
        bfr[ni] = *(const bf16x8*)(Bc + off);
      }
#pragma unroll
      for (int mi = 0; mi < 4; ++mi)
#pragma unroll
        for (int ni = 0; ni < 4; ++ni)
          acc[mi][ni] = __builtin_amdgcn_mfma_f32_16x16x32_bf16(af[mi], bfr[ni], acc[mi][ni], 0, 0, 0);
    }
    __syncthreads();
  }
#pragma unroll
  for (int ni = 0; ni < 4; ++ni) {
    int col = col0 + wn * 64 + ni * 16 + l15;
    float bv = bias[col];
#pragma unroll
    for (int mi = 0; mi < 4; ++mi)
#pragma unroll
      for (int r = 0; r < 4; ++r) {
        int row = row0 + wm * 64 + mi * 16 + lhi * 4 + r;
        Cb[(size_t)row * HID + col] = f2b(fmaxf(acc[mi][ni][r] + bv, 0.f));
      }
  }
}

// ---------------- gemm1 fallback (small-ws chunked path): r5-9 verified ----
__global__ void gatherA(const float* __restrict__ vf,
                        const unsigned int* __restrict__ eslot,
                        const unsigned int* __restrict__ ans,
                        int jbase, unsigned short* __restrict__ Ab, int mrows) {
  int idx = blockIdx.x * 256 + threadIdx.x;
  if (idx >= mrows * 32) return;
  int j = idx >> 5, c4 = (idx & 31) * 4;
  int side = (c4 < 64) ? 0 : 1;
  unsigned int r = ans[eslot[2 * (jbase + j) + side]];
  r = r < (unsigned)NPTS ? r : 0u;
  int c = (c4 < 64) ? c4 : (c4 - 64);
  float4 v = *(const float4*)&vf[(size_t)r * CFEAT + c];
  ushort4 o;
  o.x = f2b(v.x); o.y = f2b(v.y); o.z = f2b(v.z); o.w = f2b(v.w);
  *(ushort4*)&Ab[(size_t)j * KIN + c4] = o;
}

template<bool FUSE>
__global__ __launch_bounds__(256) void gemm_mfma(
    const unsigned short* __restrict__ Ab, const unsigned short* __restrict__ Bt,
    const float* __restrict__ bias, const float* __restrict__ W3,
    unsigned short* __restrict__ Cb, float* __restrict__ partial,
    int M, int N, int K) {
  __shared__ unsigned short As[128 * 64];
  __shared__ unsigned short Bs[128 * 64];
  int t = threadIdx.x;
  int lane = t & 63, w = t >> 6;
  int l15 = lane & 15, lhi = lane >> 4;
  int wm = w >> 1, wn = w & 1;
  int ncol = gridDim.x;
  int stripe, cb;
  if ((gridDim.y & 7) == 0) {
    int h = blockIdx.x + ncol * blockIdx.y;
    stripe = (h & 7) + 8 * (h / (8 * ncol));
    cb = (h >> 3) % ncol;
  } else {
    stripe = blockIdx.y; cb = blockIdx.x;
  }
  int row0 = stripe * 128, col0 = cb * 128;
  size_t Kb = (size_t)K * 2;
  f32x4 acc[4][4] = {};
  const char* Ac = (const char*)As;
  const char* Bc = (const char*)Bs;
  for (int k0 = 0; k0 < K; k0 += 64) {
#pragma unroll
    for (int it = 0; it < 4; ++it) {
      int q = (it * 4 + w) * 64 + lane;
      int row = q >> 3, slot = q & 7;
      int sb = (slot * 16) ^ ((row & 7) << 4);
      const char* gA = (const char*)Ab + (size_t)(row0 + row) * Kb + (size_t)k0 * 2 + sb;
      const char* gB = (const char*)Bt + (size_t)(col0 + row) * Kb + (size_t)k0 * 2 + sb;
      char* lA = (char*)As + (it * 4 + w) * 1024;
      char* lB = (char*)Bs + (it * 4 + w) * 1024;
      __builtin_amdgcn_global_load_lds((const __attribute__((address_space(1))) void*)gA,
                                       (__attribute__((address_space(3))) void*)lA, 16, 0, 0);
      __builtin_amdgcn_global_load_lds((const __attribute__((address_space(1))) void*)gB,
                                       (__attribute__((address_space(3))) void*)lB, 16, 0, 0);
    }
    __syncthreads();
#pragma unroll
    for (int s = 0; s < 2; ++s) {
      bf16x8 af[4], bfr[4];
#pragma unroll
      for (int mi = 0; mi < 4; ++mi) {
        int row = wm * 64 + mi * 16 + l15;
        int off = row * 128 + ((s * 64 + lhi * 16) ^ ((row & 7) << 4));
        af[mi] = *(const bf16x8*)(Ac + off);
      }
#pragma unroll
      for (int ni = 0; ni < 4; ++ni) {
        int row = wn * 64 + ni * 16 + l15;
        int off = row * 128 + ((s * 64 + lhi * 16) ^ ((row & 7) << 4));
        bfr[ni] = *(const bf16x8*)(Bc + off);
      }
#pragma unroll
      for (int mi = 0; mi < 4; ++mi)
#pragma unroll
        for (int ni = 0; ni < 4; ++ni)
          acc[mi][ni] = __builtin_amdgcn_mfma_f32_16x16x32_bf16(af[mi], bfr[ni], acc[mi][ni], 0, 0, 0);
    }
    __syncthreads();
  }
  if (!FUSE) {
#pragma unroll
    for (int ni = 0; ni < 4; ++ni) {
      int col = col0 + wn * 64 + ni * 16 + l15;
      float bv = bias[col];
#pragma unroll
      for (int mi = 0; mi < 4; ++mi)
#pragma unroll
        for (int r = 0; r < 4; ++r) {
          int row = row0 + wm * 64 + mi * 16 + lhi * 4 + r;
          Cb[(size_t)row * N + col] = f2b(fmaxf(acc[mi][ni][r] + bv, 0.f));
        }
    }
  } else {
    float bb[4], ww[4];
#pragma unroll
    for (int ni = 0; ni < 4; ++ni) {
      int col = col0 + wn * 64 + ni * 16 + l15;
      bb[ni] = bias[col];
      ww[ni] = W3[col];
    }
#pragma unroll
    for (int mi = 0; mi < 4; ++mi)
#pragma unroll
      for (int r = 0; r < 4; ++r) {
        float pv = 0.f;
#pragma unroll
        for (int ni = 0; ni < 4; ++ni)
          pv += fmaxf(acc[mi][ni][r] + bb[ni], 0.f) * ww[ni];
        pv += __shfl_xor(pv, 1);
        pv += __shfl_xor(pv, 2);
        pv += __shfl_xor(pv, 4);
        pv += __shfl_xor(pv, 8);
        if (l15 == 0) {
          int row = row0 + wm * 64 + mi * 16 + lhi * 4 + r;
          partial[(size_t)row * 16 + cb * 2 + wn] = pv;
        }
      }
  }
}

// ---------------- gemm2: 8-phase 256x256 tile, BK=64, 8 waves (r8-verified)
#define BARF() do { asm volatile("" ::: "memory"); __builtin_amdgcn_s_barrier(); \
                    asm volatile("" ::: "memory"); } while (0)
#define Q_MFMA(MIB, NIB)                                                         \
  do {                                                                           \
    __builtin_amdgcn_s_setprio(1);                                               \
    _Pragma("unroll")                                                            \
    for (int mi = 0; mi < 4; ++mi)                                               \
      _Pragma("unroll")                                                          \
      for (int ni = 0; ni < 2; ++ni)                                             \
        _Pragma("unroll")                                                        \
        for (int s = 0; s < 2; ++s)                                              \
          acc[(MIB)*4 + mi][(NIB)*2 + ni] = __builtin_amdgcn_mfma_f32_16x16x32_bf16( \
              af[mi][s], bfr[(NIB)*2 + ni][s], acc[(MIB)*4 + mi][(NIB)*2 + ni], 0, 0, 0); \
    __builtin_amdgcn_s_setprio(0);                                               \
  } while (0)

__global__ __launch_bounds__(512, 2) void gemm2_8phase(
    const unsigned short* __restrict__ Ab, const unsigned short* __restrict__ Bt,
    const float* __restrict__ bias, const float* __restrict__ W3,
    float* __restrict__ partial, int M, int N, int K) {
  __shared__ char SM[131072];
  const int t = threadIdx.x;
  const int lane = t & 63;
  const int w = t >> 6;
  const int l15 = lane & 15, lhi = lane >> 4;
  const int wm = w >> 2, wn = w & 3;
  const int ncol = gridDim.x;
  const int h = blockIdx.x + ncol * blockIdx.y;
  const int stripe = (h & 7) + 8 * (h / (8 * ncol));
  const int cb = (h >> 3) % ncol;
  const int row0 = stripe * 256, col0 = cb * 256;
  const size_t Kb = (size_t)K * 2;
  const int nt = K >> 6;

  f32x4 acc[8][4] = {};

  auto STA = [&](int bq, int qa, int kt) {
    int rho = t >> 3, slot = t & 7;
    const char* g = (const char*)Ab + (size_t)(row0 + qa * 64 + rho) * Kb
                    + (size_t)kt * 128 + ((slot * 16) ^ ((rho & 7) << 4));
    char* l = SM + bq * 32768 + qa * 8192 + t * 16;
    __builtin_amdgcn_global_load_lds((const __attribute__((address_space(1))) void*)g,
                                     (__attribute__((address_space(3))) void*)l, 16, 0, 0);
  };
  auto STB = [&](int bq, int qb, int kt) {
    int rho = t >> 3, slot = t & 7;
    const char* g = (const char*)Bt + (size_t)(col0 + qb * 64 + rho) * Kb
                    + (size_t)kt * 128 + ((slot * 16) ^ ((rho & 7) << 4));
    char* l = SM + 65536 + bq * 32768 + qb * 8192 + t * 16;
    __builtin_amdgcn_global_load_lds((const __attribute__((address_space(1))) void*)g,
                                     (__attribute__((address_space(3))) void*)l, 16, 0, 0);
  };
  auto LDA = [&](int bq, int mi, int s) -> bf16x8 {
    int r = wm * 128 + mi * 16 + l15;
    int rho = r & 63;
    return *(const bf16x8*)(SM + bq * 32768 + (r >> 6) * 8192 + rho * 128
                            + ((s * 64 + lhi * 16) ^ ((rho & 7) << 4)));
  };
  auto LDB = [&](int bq, int ni, int s) -> bf16x8 {
    int r = wn * 64 + ni * 16 + l15;
    int rho = r & 63;
    return *(const bf16x8*)(SM + 65536 + bq * 32768 + (r >> 6) * 8192 + rho * 128
                            + ((s * 64 + lhi * 16) ^ ((rho & 7) << 4)));
  };

  STA(0, 0, 0); STA(0, 2, 0); STB(0, 0, 0); STB(0, 1, 0);
  STA(0, 1, 0); STA(0, 3, 0); STB(0, 2, 0); STB(0, 3, 0);
  if (nt > 1) { STA(1, 0, 1); STA(1, 2, 1); STB(1, 0, 1); STB(1, 1, 1);
                STA(1, 1, 1); STA(1, 3, 1); }
  asm volatile("s_waitcnt vmcnt(6)" ::: "memory");
  __builtin_amdgcn_s_barrier();
  asm volatile("" ::: "memory");

  bf16x8 af[4][2], bfr[4][2];
  for (int tt = 0; tt < nt; ++tt) {
    const int bq = tt & 1, nb = bq ^ 1;
#pragma unroll
    for (int mi = 0; mi < 4; ++mi)
#pragma unroll
      for (int s = 0; s < 2; ++s) af[mi][s] = LDA(bq, mi, s);
#pragma unroll
    for (int ni = 0; ni < 4; ++ni)
#pragma unroll
      for (int s = 0; s < 2; ++s) bfr[ni][s] = LDB(bq, ni, s);
    if (tt + 1 < nt) { STB(nb, 2, tt + 1); STB(nb, 3, tt + 1); }
    BARF();
    Q_MFMA(0, 0);
    BARF();
    if (tt + 2 < nt) { STA(bq, 0, tt + 2); STA(bq, 2, tt + 2); }
    BARF();
    Q_MFMA(0, 1);
    BARF();
#pragma unroll
    for (int mi = 0; mi < 4; ++mi)
#pragma unroll
      for (int s = 0; s < 2; ++s) af[mi][s] = LDA(bq, 4 + mi, s);
    if (tt + 2 < nt) { STB(bq, 0, tt + 2); STB(bq, 1, tt + 2); }
    BARF();
    Q_MFMA(1, 0);
    BARF();
    if (tt + 2 < nt) { STA(bq, 1, tt + 2); STA(bq, 3, tt + 2); }
    BARF();
    Q_MFMA(1, 1);
    asm volatile("s_waitcnt vmcnt(6)" ::: "memory");
    BARF();
  }

  float bb[4], ww[4];
#pragma unroll
  for (int ni = 0; ni < 4; ++ni) {
    int col = col0 + wn * 64 + ni * 16 + l15;
    bb[ni] = bias[col];
    ww[ni] = W3[col];
  }
#pragma unroll
  for (int mi = 0; mi < 8; ++mi)
#pragma unroll
    for (int r = 0; r < 4; ++r) {
      float pv = 0.f;
#pragma unroll
      for (int ni = 0; ni < 4; ++ni)
        pv += fmaxf(acc[mi][ni][r] + bb[ni], 0.f) * ww[ni];
      pv += __shfl_xor(pv, 1);
      pv += __shfl_xor(pv, 2);
      pv += __shfl_xor(pv, 4);
      pv += __shfl_xor(pv, 8);
      if (l15 == 0) {
        int row = row0 + wm * 128 + mi * 16 + lhi * 4 + r;
        partial[(size_t)row * 16 + cb * 4 + wn] = pv;
      }
    }
}

// ---------------- rank + mse: pred fused in (same summation order) ---------
__global__ __launch_bounds__(256) void rank_kernel(
    const float* __restrict__ partial, const float* __restrict__ b3,
    const float* __restrict__ rew,
    double* __restrict__ rank_part, unsigned int* __restrict__ cnt_part,
    double* __restrict__ mse_part) {
  int b = blockIdx.x;
  int jb = blockIdx.y;
  __shared__ float pb[PP];
  __shared__ float tb[PP];
  int t = threadIdx.x;
  float b3v = b3[0];
  for (int i = t; i < PP; i += 256) {
    float s = b3v;
    const float* pr = &partial[(size_t)(b * PP + i) * 16];
#pragma unroll
    for (int nb = 0; nb < 16; ++nb) s += pr[nb];   // same order as old pred
    pb[i] = s;
    tb[i] = rew[b * PP + i];
  }
  __syncthreads();
  float tj[RJ], pj[RJ];
  int j0 = jb * RJ;
#pragma unroll
  for (int r = 0; r < RJ; ++r) { tj[r] = tb[j0 + r]; pj[r] = pb[j0 + r]; }
  float fs = 0.f;
  unsigned int c = 0;
  for (int i = t; i < PP; i += 256) {
    float ti = tb[i], pi = pb[i];
#pragma unroll
    for (int r = 0; r < RJ; ++r) {
      float dt = ti - tj[r];
      float dp = pi - pj[r];
      float z = dt > 0.f ? -dp : dp;
      float e = __expf(-fabsf(z));
      float sp = fmaxf(z, 0.f) + __logf(1.f + e);
      bool v = dt != 0.f;
      fs += v ? sp : 0.f;
      c += v ? 1u : 0u;
    }
  }
  float msep = 0.f;
  if (jb == 0) {
    for (int i = t; i < PP; i += 256) {
      float d = pb[i] - tb[i];
      msep = fmaf(d, d, msep);
    }
  }
  __shared__ double sred[256];
  __shared__ unsigned int cred[256];
  __shared__ float mred[256];
  sred[t] = (double)fs; cred[t] = c; mred[t] = msep;
  __syncthreads();
  for (int off = 128; off > 0; off >>= 1) {
    if (t < off) {
      sred[t] += sred[t + off];
      cred[t] += cred[t + off];
      mred[t] += mred[t + off];
    }
    __syncthreads();
  }
  if (t == 0) {
    rank_part[b * NJB + jb] = sred[0];
    cnt_part[b * NJB + jb] = cred[0];
    if (jb == 0) mse_part[b] = (double)mred[0];
  }
}

// ---------------- finalize: 16 lanes reduce per-batch, lane 0 combines -----
__global__ void finalize_kernel(const double* __restrict__ rank_part,
                                const unsigned int* __restrict__ cnt_part,
                                const double* __restrict__ mse_part,
                                float* __restrict__ out) {
  __shared__ double rls[16];
  __shared__ double mss[16];
  __shared__ int hasv[16];
  int t = threadIdx.x;
  if (t < BATCH) {
    double s = 0.0;
    ull c = 0;
    for (int jb = 0; jb < NJB; ++jb) {
      s += rank_part[t * NJB + jb];
      c += cnt_part[t * NJB + jb];
    }
    rls[t] = c > 0 ? s / (double)c : 0.0;
    hasv[t] = c > 0 ? 1 : 0;
    mss[t] = mse_part[t] / (double)PP;
  }
  __syncthreads();
  if (t == 0) {
    double rl = 0.0, ms = 0.0;
    int has = 0;
    for (int b = 0; b < BATCH; ++b) { rl += rls[b]; has += hasv[b]; ms += mss[b]; }
    double rank_loss = rl / (double)(has > 0 ? has : 1);
    double mse_loss = ms / (double)BATCH;
    out[0] = (float)(rank_loss + 0.1 * mse_loss);
  }
}

// ---------------------------------------------------------------------------
extern "C" void kernel_launch(void* const* d_in, const int* in_sizes, int n_in,
                              void* d_out, int out_size, void* d_ws, size_t ws_size,
                              hipStream_t stream) {
  const float* vf   = (const float*)d_in[0];
  const float* rew  = (const float*)d_in[1];
  const float* W1   = (const float*)d_in[2];
  const float* b1   = (const float*)d_in[3];
  const float* W2   = (const float*)d_in[4];
  const float* b2   = (const float*)d_in[5];
  const float* W3   = (const float*)d_in[6];
  const float* b3   = (const float*)d_in[7];
  const int*   gc   = (const int*)d_in[8];
  const int*   vidx  = (const int*)d_in[10];   // int32 (harness converts int64)
  const int*   pairs = (const int*)d_in[11];   // int32

  char* ws = (char*)d_ws;
  size_t off = 0;
  auto alloc = [&](size_t bytes) -> void* {
    void* p = ws + off;
    off += (bytes + 255) & ~(size_t)255;
    return p;
  };
  ull* qtable          = (ull*)alloc((size_t)QTS * 8);
  unsigned int* eslot  = (unsigned int*)alloc((size_t)NEND * 4);
  unsigned int* ans    = (unsigned int*)alloc((size_t)QTS * 4);
  float* partial       = (float*)alloc((size_t)NPAIR * 16 * 4);
  double* rank_part    = (double*)alloc((size_t)BATCH * NJB * 8);
  unsigned int* cnt_p  = (unsigned int*)alloc((size_t)BATCH * NJB * 4);
  double* mse_part     = (double*)alloc((size_t)BATCH * 8);
  unsigned short* Wt1  = (unsigned short*)alloc((size_t)HID * KIN * 2);
  unsigned short* Wt2  = (unsigned short*)alloc((size_t)HID * HID * 2);

  int mchunk = 2048;
  for (int cand = NPAIR; cand >= 2048; cand >>= 1) {
    size_t need = off + (size_t)cand * (KIN * 2 + HID * 2) + 2 * 65536;
    if (need <= ws_size) { mchunk = cand; break; }
  }
  unsigned short* h1 = (unsigned short*)alloc((size_t)mchunk * HID * 2);

  setup_kernel<<<2048, 256, 0, stream>>>(qtable, ans, W1, Wt1, W2, Wt2);
  qinsert<<<(NEND + 255) / 256, 256, 0, stream>>>(pairs, gc, qtable, eslot);
  vscan<<<(NPTS + 255) / 256, 256, 0, stream>>>(vidx, qtable, ans);

  if (mchunk == NPAIR) {
    // single-chunk fast path: gather fused into gemm1, 7 dispatches total
    dim3 g1(HID / 128, NPAIR / 128);
    gemm1_fused<<<g1, 256, 0, stream>>>(vf, eslot, ans, Wt1, b1, h1, NPAIR);
    dim3 g2(HID / 256, NPAIR / 256);
    gemm2_8phase<<<g2, 512, 0, stream>>>(h1, Wt2, b2, W3, partial, NPAIR, HID, HID);
  } else {
    // small-ws fallback: chunked, separate gather (r5-9 verified path)
    unsigned short* Ab = (unsigned short*)alloc((size_t)mchunk * KIN * 2);
    int nchunk = NPAIR / mchunk;
    for (int ch = 0; ch < nchunk; ++ch) {
      gatherA<<<(mchunk * 32 + 255) / 256, 256, 0, stream>>>(
          vf, eslot, ans, ch * mchunk, Ab, mchunk);
      dim3 g1(HID / 128, mchunk / 128);
      gemm_mfma<false><<<g1, 256, 0, stream>>>(Ab, Wt1, b1, nullptr, h1, nullptr,
                                               mchunk, HID, KIN);
      if (mchunk >= 512 && (mchunk & 255) == 0) {
        dim3 g2(HID / 256, mchunk / 256);
        gemm2_8phase<<<g2, 512, 0, stream>>>(h1, Wt2, b2, W3,
                                             partial + (size_t)ch * mchunk * 16,
                                             mchunk, HID, HID);
      } else {
        dim3 g2(HID / 128, mchunk / 128);
        gemm_mfma<true><<<g2, 256, 0, stream>>>(h1, Wt2, b2, W3, nullptr,
                                                partial + (size_t)ch * mchunk * 16,
                                                mchunk, HID, HID);
      }
    }
  }

  rank_kernel<<<dim3(BATCH, NJB), 256, 0, stream>>>(partial, b3, rew,
                                                    rank_part, cnt_p, mse_part);
  finalize_kernel<<<1, 64, 0, stream>>>(rank_part, cnt_p, mse_part, (float*)d_out);
}

// Round 11
// 181.726 us; speedup vs baseline: 1.1336x; 1.1336x over previous
//
#include <hip/hip_runtime.h>
#include <stdint.h>

#define BATCH   16
#define PTS     50000
#define PP      2048
#define NPTS    (BATCH*PTS)     // 800000
#define NPAIR   (BATCH*PP)      // 32768
#define NEND    (2*NPAIR)
#define CFEAT   64
#define KIN     128             // folded layer-1 K
#define HID     1024
#define QTS_LOG2 17
#define QTS     (1u<<QTS_LOG2)
#define QTS_MASK (QTS-1)
#define EMPTY_KEY 0xFFFFFFFFFFFFFFFFULL
#define NJB     64
#define RJ      (PP/NJB)        // 32 j's per block, in registers

typedef unsigned long long ull;
typedef __attribute__((ext_vector_type(4))) float f32x4;
typedef __attribute__((ext_vector_type(8))) short bf16x8;

__device__ __forceinline__ ull mix64(ull h) {
  h ^= h >> 33; h *= 0xff51afd7ed558ccdULL;
  h ^= h >> 33; h *= 0xc4ceb9fe1a85ec53ULL;
  h ^= h >> 33; return h;
}

__device__ __forceinline__ unsigned short f2b(float x) {  // fp32->bf16 RNE
  unsigned u = __float_as_uint(x);
  unsigned r = (u + 0x7FFFu + ((u >> 16) & 1u)) >> 16;
  return (unsigned short)r;
}

// ---------------- setup: hash-init + foldW1 + transcvt(W2), one dispatch ---
__global__ __launch_bounds__(256) void setup_kernel(
    ull* __restrict__ qtable, unsigned int* __restrict__ ans,
    const float* __restrict__ W1, unsigned short* __restrict__ Wt1,
    const float* __restrict__ W2, unsigned short* __restrict__ Wt2) {
  __shared__ unsigned short tile[32][33];
  int bid = blockIdx.x;
  int t = threadIdx.x;
  if (bid < 512) {
    int i = bid * 256 + t;                  // QTS = 131072 = 512*256
    qtable[i] = EMPTY_KEY;
    ans[i] = 0xFFFFFFFFu;
  } else if (bid < 1024) {
    int idx = (bid - 512) * 256 + t;        // HID*KIN = 131072
    int n = idx >> 7, k = idx & 127;
    float v;
    if (k < 64)
      v = W1[(size_t)k * HID + n] + W1[(size_t)(128 + k) * HID + n];
    else
      v = W1[(size_t)k * HID + n] - W1[(size_t)(64 + k) * HID + n];
    Wt1[(size_t)n * KIN + k] = f2b(v);
  } else {
    int b = bid - 1024;                     // 1024 blocks: 32x32 tiles of W2
    int nb = (b & 31) * 32, kb = (b >> 5) * 32;
    int tx = t & 31, ty = t >> 5;
#pragma unroll
    for (int r = 0; r < 32; r += 8)
      tile[ty + r][tx] = f2b(W2[(size_t)(kb + ty + r) * HID + nb + tx]);
    __syncthreads();
#pragma unroll
    for (int r = 0; r < 32; r += 8)
      Wt2[(size_t)(nb + ty + r) * HID + kb + tx] = tile[tx][ty + r];
  }
}

// ---------------- insert the 65536 endpoint keys ---------------------------
__global__ void qinsert(const int* __restrict__ pairs, const int* __restrict__ gc,
                        ull* __restrict__ qtable, unsigned int* __restrict__ eslot) {
  int e = blockIdx.x * blockDim.x + threadIdx.x;
  if (e >= NEND) return;
  int j = e >> 1, side = e & 1;
  int seg = j / PP;
  int pi = pairs[2*j + side] + seg * PTS;
  pi = pi < 0 ? 0 : (pi >= NPTS ? NPTS - 1 : pi);
  ull key = ((ull)seg << 30) | ((ull)(gc[3*pi] & 1023) << 20)
          | ((ull)(gc[3*pi+1] & 1023) << 10) | (ull)(gc[3*pi+2] & 1023);
  unsigned int h = (unsigned int)mix64(key) & QTS_MASK;
  for (int p = 0; p < (int)QTS; ++p) {
    ull prev = atomicCAS(&qtable[h], EMPTY_KEY, key);
    if (prev == EMPTY_KEY || prev == key) { eslot[e] = h; return; }
    h = (h + 1) & QTS_MASK;
  }
  eslot[e] = 0;
}

// ---------------- scan all voxels; min row index per queried key -----------
__global__ void vscan(const int* __restrict__ vidx, const ull* __restrict__ qtable,
                      unsigned int* __restrict__ ans) {
  int i = blockIdx.x * blockDim.x + threadIdx.x;
  if (i >= NPTS) return;
  int4 v = *(const int4*)&vidx[4*i];
  ull key = ((ull)(v.x & 31) << 30) | ((ull)(v.y & 1023) << 20)
          | ((ull)(v.z & 1023) << 10) | (ull)(v.w & 1023);
  unsigned int h = (unsigned int)mix64(key) & QTS_MASK;
  for (int p = 0; p < (int)QTS; ++p) {
    ull k = qtable[h];
    if (k == key) { atomicMin(&ans[h], (unsigned int)i); return; }
    if (k == EMPTY_KEY) return;
    h = (h + 1) & QTS_MASK;
  }
}

// ---------------- gather pair features bf16 A [mrows][128] = [f0, f1] ------
__global__ void gatherA(const float* __restrict__ vf,
                        const unsigned int* __restrict__ eslot,
                        const unsigned int* __restrict__ ans,
                        int jbase, unsigned short* __restrict__ Ab, int mrows) {
  int idx = blockIdx.x * 256 + threadIdx.x;
  if (idx >= mrows * 32) return;
  int j = idx >> 5, c4 = (idx & 31) * 4;
  int side = (c4 < 64) ? 0 : 1;
  unsigned int r = ans[eslot[2 * (jbase + j) + side]];
  r = r < (unsigned)NPTS ? r : 0u;       // wrong-value beats mem-fault
  int c = (c4 < 64) ? c4 : (c4 - 64);
  float4 v = *(const float4*)&vf[(size_t)r * CFEAT + c];
  ushort4 o;
  o.x = f2b(v.x); o.y = f2b(v.y); o.z = f2b(v.z); o.w = f2b(v.w);
  *(ushort4*)&Ab[(size_t)j * KIN + c4] = o;
}

// ---------------- gemm1: bf16 MFMA, 128x128 tile, BK=64, 4 waves (r5-9) ----
template<bool FUSE>
__global__ __launch_bounds__(256) void gemm_mfma(
    const unsigned short* __restrict__ Ab, const unsigned short* __restrict__ Bt,
    const float* __restrict__ bias, const float* __restrict__ W3,
    unsigned short* __restrict__ Cb, float* __restrict__ partial,
    int M, int N, int K) {
  __shared__ unsigned short As[128 * 64];
  __shared__ unsigned short Bs[128 * 64];
  int t = threadIdx.x;
  int lane = t & 63, w = t >> 6;
  int l15 = lane & 15, lhi = lane >> 4;
  int wm = w >> 1, wn = w & 1;
  int ncol = gridDim.x;
  int stripe, cb;
  if ((gridDim.y & 7) == 0) {
    int h = blockIdx.x + ncol * blockIdx.y;
    stripe = (h & 7) + 8 * (h / (8 * ncol));
    cb = (h >> 3) % ncol;
  } else {
    stripe = blockIdx.y; cb = blockIdx.x;
  }
  int row0 = stripe * 128, col0 = cb * 128;
  size_t Kb = (size_t)K * 2;
  f32x4 acc[4][4] = {};
  const char* Ac = (const char*)As;
  const char* Bc = (const char*)Bs;
  for (int k0 = 0; k0 < K; k0 += 64) {
#pragma unroll
    for (int it = 0; it < 4; ++it) {
      int q = (it * 4 + w) * 64 + lane;
      int row = q >> 3, slot = q & 7;
      int sb = (slot * 16) ^ ((row & 7) << 4);
      const char* gA = (const char*)Ab + (size_t)(row0 + row) * Kb + (size_t)k0 * 2 + sb;
      const char* gB = (const char*)Bt + (size_t)(col0 + row) * Kb + (size_t)k0 * 2 + sb;
      char* lA = (char*)As + (it * 4 + w) * 1024;
      char* lB = (char*)Bs + (it * 4 + w) * 1024;
      __builtin_amdgcn_global_load_lds((const __attribute__((address_space(1))) void*)gA,
                                       (__attribute__((address_space(3))) void*)lA, 16, 0, 0);
      __builtin_amdgcn_global_load_lds((const __attribute__((address_space(1))) void*)gB,
                                       (__attribute__((address_space(3))) void*)lB, 16, 0, 0);
    }
    __syncthreads();
#pragma unroll
    for (int s = 0; s < 2; ++s) {
      bf16x8 af[4], bfr[4];
#pragma unroll
      for (int mi = 0; mi < 4; ++mi) {
        int row = wm * 64 + mi * 16 + l15;
        int off = row * 128 + ((s * 64 + lhi * 16) ^ ((row & 7) << 4));
        af[mi] = *(const bf16x8*)(Ac + off);
      }
#pragma unroll
      for (int ni = 0; ni < 4; ++ni) {
        int row = wn * 64 + ni * 16 + l15;
        int off = row * 128 + ((s * 64 + lhi * 16) ^ ((row & 7) << 4));
        bfr[ni] = *(const bf16x8*)(Bc + off);
      }
#pragma unroll
      for (int mi = 0; mi < 4; ++mi)
#pragma unroll
        for (int ni = 0; ni < 4; ++ni)
          acc[mi][ni] = __builtin_amdgcn_mfma_f32_16x16x32_bf16(af[mi], bfr[ni], acc[mi][ni], 0, 0, 0);
    }
    __syncthreads();
  }
  if (!FUSE) {
#pragma unroll
    for (int ni = 0; ni < 4; ++ni) {
      int col = col0 + wn * 64 + ni * 16 + l15;
      float bv = bias[col];
#pragma unroll
      for (int mi = 0; mi < 4; ++mi)
#pragma unroll
        for (int r = 0; r < 4; ++r) {
          int row = row0 + wm * 64 + mi * 16 + lhi * 4 + r;
          Cb[(size_t)row * N + col] = f2b(fmaxf(acc[mi][ni][r] + bv, 0.f));
        }
    }
  } else {
    float bb[4], ww[4];
#pragma unroll
    for (int ni = 0; ni < 4; ++ni) {
      int col = col0 + wn * 64 + ni * 16 + l15;
      bb[ni] = bias[col];
      ww[ni] = W3[col];
    }
#pragma unroll
    for (int mi = 0; mi < 4; ++mi)
#pragma unroll
      for (int r = 0; r < 4; ++r) {
        float pv = 0.f;
#pragma unroll
        for (int ni = 0; ni < 4; ++ni)
          pv += fmaxf(acc[mi][ni][r] + bb[ni], 0.f) * ww[ni];
        pv += __shfl_xor(pv, 1);
        pv += __shfl_xor(pv, 2);
        pv += __shfl_xor(pv, 4);
        pv += __shfl_xor(pv, 8);
        if (l15 == 0) {
          int row = row0 + wm * 64 + mi * 16 + lhi * 4 + r;
          partial[(size_t)row * 16 + cb * 2 + wn] = pv;
        }
      }
  }
}

// ---------------- gemm2: 8-phase 256x256 tile, BK=64, 8 waves (r8-verified)
#define BARF() do { asm volatile("" ::: "memory"); __builtin_amdgcn_s_barrier(); \
                    asm volatile("" ::: "memory"); } while (0)
#define Q_MFMA(MIB, NIB)                                                         \
  do {                                                                           \
    __builtin_amdgcn_s_setprio(1);                                               \
    _Pragma("unroll")                                                            \
    for (int mi = 0; mi < 4; ++mi)                                               \
      _Pragma("unroll")                                                          \
      for (int ni = 0; ni < 2; ++ni)                                             \
        _Pragma("unroll")                                                        \
        for (int s = 0; s < 2; ++s)                                              \
          acc[(MIB)*4 + mi][(NIB)*2 + ni] = __builtin_amdgcn_mfma_f32_16x16x32_bf16( \
              af[mi][s], bfr[(NIB)*2 + ni][s], acc[(MIB)*4 + mi][(NIB)*2 + ni], 0, 0, 0); \
    __builtin_amdgcn_s_setprio(0);                                               \
  } while (0)

__global__ __launch_bounds__(512, 2) void gemm2_8phase(
    const unsigned short* __restrict__ Ab, const unsigned short* __restrict__ Bt,
    const float* __restrict__ bias, const float* __restrict__ W3,
    float* __restrict__ partial, int M, int N, int K) {
  __shared__ char SM[131072];
  const int t = threadIdx.x;
  const int lane = t & 63;
  const int w = t >> 6;
  const int l15 = lane & 15, lhi = lane >> 4;
  const int wm = w >> 2, wn = w & 3;
  const int ncol = gridDim.x;
  const int h = blockIdx.x + ncol * blockIdx.y;
  const int stripe = (h & 7) + 8 * (h / (8 * ncol));
  const int cb = (h >> 3) % ncol;
  const int row0 = stripe * 256, col0 = cb * 256;
  const size_t Kb = (size_t)K * 2;
  const int nt = K >> 6;

  f32x4 acc[8][4] = {};

  auto STA = [&](int bq, int qa, int kt) {
    int rho = t >> 3, slot = t & 7;
    const char* g = (const char*)Ab + (size_t)(row0 + qa * 64 + rho) * Kb
                    + (size_t)kt * 128 + ((slot * 16) ^ ((rho & 7) << 4));
    char* l = SM + bq * 32768 + qa * 8192 + t * 16;
    __builtin_amdgcn_global_load_lds((const __attribute__((address_space(1))) void*)g,
                                     (__attribute__((address_space(3))) void*)l, 16, 0, 0);
  };
  auto STB = [&](int bq, int qb, int kt) {
    int rho = t >> 3, slot = t & 7;
    const char* g = (const char*)Bt + (size_t)(col0 + qb * 64 + rho) * Kb
                    + (size_t)kt * 128 + ((slot * 16) ^ ((rho & 7) << 4));
    char* l = SM + 65536 + bq * 32768 + qb * 8192 + t * 16;
    __builtin_amdgcn_global_load_lds((const __attribute__((address_space(1))) void*)g,
                                     (__attribute__((address_space(3))) void*)l, 16, 0, 0);
  };
  auto LDA = [&](int bq, int mi, int s) -> bf16x8 {
    int r = wm * 128 + mi * 16 + l15;
    int rho = r & 63;
    return *(const bf16x8*)(SM + bq * 32768 + (r >> 6) * 8192 + rho * 128
                            + ((s * 64 + lhi * 16) ^ ((rho & 7) << 4)));
  };
  auto LDB = [&](int bq, int ni, int s) -> bf16x8 {
    int r = wn * 64 + ni * 16 + l15;
    int rho = r & 63;
    return *(const bf16x8*)(SM + 65536 + bq * 32768 + (r >> 6) * 8192 + rho * 128
                            + ((s * 64 + lhi * 16) ^ ((rho & 7) << 4)));
  };

  STA(0, 0, 0); STA(0, 2, 0); STB(0, 0, 0); STB(0, 1, 0);
  STA(0, 1, 0); STA(0, 3, 0); STB(0, 2, 0); STB(0, 3, 0);
  if (nt > 1) { STA(1, 0, 1); STA(1, 2, 1); STB(1, 0, 1); STB(1, 1, 1);
                STA(1, 1, 1); STA(1, 3, 1); }
  asm volatile("s_waitcnt vmcnt(6)" ::: "memory");
  __builtin_amdgcn_s_barrier();
  asm volatile("" ::: "memory");

  bf16x8 af[4][2], bfr[4][2];
  for (int tt = 0; tt < nt; ++tt) {
    const int bq = tt & 1, nb = bq ^ 1;
#pragma unroll
    for (int mi = 0; mi < 4; ++mi)
#pragma unroll
      for (int s = 0; s < 2; ++s) af[mi][s] = LDA(bq, mi, s);
#pragma unroll
    for (int ni = 0; ni < 4; ++ni)
#pragma unroll
      for (int s = 0; s < 2; ++s) bfr[ni][s] = LDB(bq, ni, s);
    if (tt + 1 < nt) { STB(nb, 2, tt + 1); STB(nb, 3, tt + 1); }
    BARF();
    Q_MFMA(0, 0);
    BARF();
    if (tt + 2 < nt) { STA(bq, 0, tt + 2); STA(bq, 2, tt + 2); }
    BARF();
    Q_MFMA(0, 1);
    BARF();
#pragma unroll
    for (int mi = 0; mi < 4; ++mi)
#pragma unroll
      for (int s = 0; s < 2; ++s) af[mi][s] = LDA(bq, 4 + mi, s);
    if (tt + 2 < nt) { STB(bq, 0, tt + 2); STB(bq, 1, tt + 2); }
    BARF();
    Q_MFMA(1, 0);
    BARF();
    if (tt + 2 < nt) { STA(bq, 1, tt + 2); STA(bq, 3, tt + 2); }
    BARF();
    Q_MFMA(1, 1);
    asm volatile("s_waitcnt vmcnt(6)" ::: "memory");
    BARF();
  }

  float bb[4], ww[4];
#pragma unroll
  for (int ni = 0; ni < 4; ++ni) {
    int col = col0 + wn * 64 + ni * 16 + l15;
    bb[ni] = bias[col];
    ww[ni] = W3[col];
  }
#pragma unroll
  for (int mi = 0; mi < 8; ++mi)
#pragma unroll
    for (int r = 0; r < 4; ++r) {
      float pv = 0.f;
#pragma unroll
      for (int ni = 0; ni < 4; ++ni)
        pv += fmaxf(acc[mi][ni][r] + bb[ni], 0.f) * ww[ni];
      pv += __shfl_xor(pv, 1);
      pv += __shfl_xor(pv, 2);
      pv += __shfl_xor(pv, 4);
      pv += __shfl_xor(pv, 8);
      if (l15 == 0) {
        int row = row0 + wm * 128 + mi * 16 + lhi * 4 + r;
        partial[(size_t)row * 16 + cb * 4 + wn] = pv;
      }
    }
}

// ---------------- rank + mse: pred fused; TRIU-ONLY (j < i), exact ref sum -
// softplus arg is swap-symmetric, so the reference triu sum/cnt is computed
// directly: window [j0,j0+RJ), i ranges j0+1..PP-1, predicate r < i-j0.
__global__ __launch_bounds__(256) void rank_kernel(
    const float* __restrict__ partial, const float* __restrict__ b3,
    const float* __restrict__ rew,
    double* __restrict__ rank_part, unsigned int* __restrict__ cnt_part,
    double* __restrict__ mse_part) {
  int b = blockIdx.x;
  int jb = blockIdx.y;
  __shared__ float pb[PP];
  __shared__ float tb[PP];
  int t = threadIdx.x;
  float b3v = b3[0];
  for (int i = t; i < PP; i += 256) {
    float s = b3v;
    const float* pr = &partial[(size_t)(b * PP + i) * 16];
#pragma unroll
    for (int nb = 0; nb < 16; ++nb) s += pr[nb];   // same order as old pred
    pb[i] = s;
    tb[i] = rew[b * PP + i];
  }
  __syncthreads();
  float tj[RJ], pj[RJ];
  int j0 = jb * RJ;
#pragma unroll
  for (int r = 0; r < RJ; ++r) { tj[r] = tb[j0 + r]; pj[r] = pb[j0 + r]; }
  float fs = 0.f;
  unsigned int c = 0;
  for (int i = j0 + 1 + t; i < PP; i += 256) {
    float ti = tb[i], pi = pb[i];
    int lim = i - j0;                      // pairs with r < lim have j < i
#pragma unroll
    for (int r = 0; r < RJ; ++r) {
      float dt = ti - tj[r];
      float dp = pi - pj[r];
      float z = dt > 0.f ? -dp : dp;
      float e = __expf(-fabsf(z));
      float sp = fmaxf(z, 0.f) + __logf(1.f + e);
      bool v = (r < lim) && (dt != 0.f);
      fs += v ? sp : 0.f;
      c += v ? 1u : 0u;
    }
  }
  float msep = 0.f;
  if (jb == 0) {
    for (int i = t; i < PP; i += 256) {
      float d = pb[i] - tb[i];
      msep = fmaf(d, d, msep);
    }
  }
  __shared__ double sred[256];
  __shared__ unsigned int cred[256];
  __shared__ float mred[256];
  sred[t] = (double)fs; cred[t] = c; mred[t] = msep;
  __syncthreads();
  for (int off = 128; off > 0; off >>= 1) {
    if (t < off) {
      sred[t] += sred[t + off];
      cred[t] += cred[t + off];
      mred[t] += mred[t + off];
    }
    __syncthreads();
  }
  if (t == 0) {
    rank_part[b * NJB + jb] = sred[0];
    cnt_part[b * NJB + jb] = cred[0];
    if (jb == 0) mse_part[b] = (double)mred[0];
  }
}

// ---------------- finalize: 16 lanes reduce per-batch, lane 0 combines -----
__global__ void finalize_kernel(const double* __restrict__ rank_part,
                                const unsigned int* __restrict__ cnt_part,
                                const double* __restrict__ mse_part,
                                float* __restrict__ out) {
  __shared__ double rls[16];
  __shared__ double mss[16];
  __shared__ int hasv[16];
  int t = threadIdx.x;
  if (t < BATCH) {
    double s = 0.0;
    ull c = 0;
    for (int jb = 0; jb < NJB; ++jb) {
      s += rank_part[t * NJB + jb];
      c += cnt_part[t * NJB + jb];
    }
    rls[t] = c > 0 ? s / (double)c : 0.0;
    hasv[t] = c > 0 ? 1 : 0;
    mss[t] = mse_part[t] / (double)PP;
  }
  __syncthreads();
  if (t == 0) {
    double rl = 0.0, ms = 0.0;
    int has = 0;
    for (int b = 0; b < BATCH; ++b) { rl += rls[b]; has += hasv[b]; ms += mss[b]; }
    double rank_loss = rl / (double)(has > 0 ? has : 1);
    double mse_loss = ms / (double)BATCH;
    out[0] = (float)(rank_loss + 0.1 * mse_loss);
  }
}

// ---------------------------------------------------------------------------
extern "C" void kernel_launch(void* const* d_in, const int* in_sizes, int n_in,
                              void* d_out, int out_size, void* d_ws, size_t ws_size,
                              hipStream_t stream) {
  const float* vf   = (const float*)d_in[0];
  const float* rew  = (const float*)d_in[1];
  const float* W1   = (const float*)d_in[2];
  const float* b1   = (const float*)d_in[3];
  const float* W2   = (const float*)d_in[4];
  const float* b2   = (const float*)d_in[5];
  const float* W3   = (const float*)d_in[6];
  const float* b3   = (const float*)d_in[7];
  const int*   gc   = (const int*)d_in[8];
  const int*   vidx  = (const int*)d_in[10];   // int32 (harness converts int64)
  const int*   pairs = (const int*)d_in[11];   // int32

  char* ws = (char*)d_ws;
  size_t off = 0;
  auto alloc = [&](size_t bytes) -> void* {
    void* p = ws + off;
    off += (bytes + 255) & ~(size_t)255;
    return p;
  };
  ull* qtable          = (ull*)alloc((size_t)QTS * 8);
  unsigned int* eslot  = (unsigned int*)alloc((size_t)NEND * 4);
  unsigned int* ans    = (unsigned int*)alloc((size_t)QTS * 4);
  float* partial       = (float*)alloc((size_t)NPAIR * 16 * 4);
  double* rank_part    = (double*)alloc((size_t)BATCH * NJB * 8);
  unsigned int* cnt_p  = (unsigned int*)alloc((size_t)BATCH * NJB * 4);
  double* mse_part     = (double*)alloc((size_t)BATCH * 8);
  unsigned short* Wt1  = (unsigned short*)alloc((size_t)HID * KIN * 2);
  unsigned short* Wt2  = (unsigned short*)alloc((size_t)HID * HID * 2);

  int mchunk = 2048;
  for (int cand = NPAIR; cand >= 2048; cand >>= 1) {
    size_t need = off + (size_t)cand * (KIN * 2 + HID * 2) + 2 * 65536;
    if (need <= ws_size) { mchunk = cand; break; }
  }
  unsigned short* Ab = (unsigned short*)alloc((size_t)mchunk * KIN * 2);
  unsigned short* h1 = (unsigned short*)alloc((size_t)mchunk * HID * 2);

  setup_kernel<<<2048, 256, 0, stream>>>(qtable, ans, W1, Wt1, W2, Wt2);
  qinsert<<<(NEND + 255) / 256, 256, 0, stream>>>(pairs, gc, qtable, eslot);
  vscan<<<(NPTS + 255) / 256, 256, 0, stream>>>(vidx, qtable, ans);

  int nchunk = NPAIR / mchunk;
  for (int ch = 0; ch < nchunk; ++ch) {
    gatherA<<<(mchunk * 32 + 255) / 256, 256, 0, stream>>>(
        vf, eslot, ans, ch * mchunk, Ab, mchunk);
    dim3 g1(HID / 128, mchunk / 128);
    gemm_mfma<false><<<g1, 256, 0, stream>>>(Ab, Wt1, b1, nullptr, h1, nullptr,
                                             mchunk, HID, KIN);
    if (mchunk >= 512 && (mchunk & 255) == 0) {
      dim3 g2(HID / 256, mchunk / 256);
      gemm2_8phase<<<g2, 512, 0, stream>>>(h1, Wt2, b2, W3,
                                           partial + (size_t)ch * mchunk * 16,
                                           mchunk, HID, HID);
    } else {
      dim3 g2(HID / 128, mchunk / 128);
      gemm_mfma<true><<<g2, 256, 0, stream>>>(h1, Wt2, b2, W3, nullptr,
                                              partial + (size_t)ch * mchunk * 16,
                                              mchunk, HID, HID);
    }
  }

  rank_kernel<<<dim3(BATCH, NJB), 256, 0, stream>>>(partial, b3, rew,
                                                    rank_part, cnt_p, mse_part);
  finalize_kernel<<<1, 64, 0, stream>>>(rank_part, cnt_p, mse_part, (float*)d_out);
}